// Round 4
// baseline (626.195 us; speedup 1.0000x reference)
//
#include <hip/hip_runtime.h>
#include <math.h>

#define NLAYER 4
#define DMODEL 640
#define DINNER 1280
#define DSTATE 16
#define DTRANK 40
#define DCONV  4
#define BATCH  64
#define SEQ    30
#define MTOK   (BATCH*SEQ)       // 1920
#define NPROJ  (2*DINNER)        // 2560
#define NDBL   (DTRANK+2*DSTATE) // 72
#define NDBLP  80                // padded N for x_proj MFMA

typedef unsigned short u16;
typedef __bf16 bf16x8 __attribute__((ext_vector_type(8)));
typedef float  f32x4  __attribute__((ext_vector_type(4)));

__device__ __forceinline__ float siluf(float x) {
    return x / (1.0f + __expf(-x));
}

__device__ __forceinline__ u16 f2bf(float f) {
    unsigned int u = __float_as_uint(f);
    u += 0x7fffu + ((u >> 16) & 1u);
    return (u16)(u >> 16);
}

__device__ __forceinline__ float bf2f(u16 b) {
    return __uint_as_float(((unsigned int)b) << 16);
}

// h[b,v,:] = x[b,(v + SEQ - vs[b]) % SEQ, :]
__global__ void k_permute(const float* __restrict__ x, const int* __restrict__ vs,
                          float* __restrict__ h) {
    int idx = blockIdx.x * blockDim.x + threadIdx.x;
    if (idx >= MTOK * DMODEL) return;
    int d  = idx % DMODEL;
    int mv = idx / DMODEL;
    int v  = mv % SEQ;
    int b  = mv / SEQ;
    int src = (v + SEQ - vs[b]) % SEQ;
    h[idx] = x[(b * SEQ + src) * DMODEL + d];
}

// fp32 -> bf16, 4/thread
__global__ void k_f2bf(const float* __restrict__ src, u16* __restrict__ dst, int n) {
    int i = (blockIdx.x * blockDim.x + threadIdx.x) * 4;
    if (i >= n) return;
    float4 v = *(const float4*)(src + i);
    ushort4 o;
    o.x = f2bf(v.x); o.y = f2bf(v.y); o.z = f2bf(v.z); o.w = f2bf(v.w);
    *(ushort4*)(dst + i) = o;
}

// xp_w [4][72][1280] fp32 -> [4][80][1280] bf16, rows 72..79 of each layer zeroed
__global__ void k_f2bf_pad4(const float* __restrict__ src, u16* __restrict__ dst) {
    int i = (blockIdx.x * blockDim.x + threadIdx.x) * 4;
    if (i >= NLAYER * NDBLP * DINNER) return;
    int layer = i / (NDBLP * DINNER);
    int rem   = i % (NDBLP * DINNER);
    int row   = rem / DINNER;
    int col   = rem % DINNER;
    ushort4 o = make_ushort4(0, 0, 0, 0);
    if (row < NDBL) {
        float4 v = *(const float4*)(src + (size_t)layer * NDBL * DINNER
                                        + (size_t)row * DINNER + col);
        o.x = f2bf(v.x); o.y = f2bf(v.y); o.z = f2bf(v.z); o.w = f2bf(v.w);
    }
    *(ushort4*)(dst + i) = o;
}

// one wave per token: xn_bf16 = h * rsqrt(mean(h^2)+eps) * w
__global__ __launch_bounds__(64)
void k_rmsnorm(const float* __restrict__ h, const float* __restrict__ w,
               u16* __restrict__ xn) {
    int m = blockIdx.x;
    int t = threadIdx.x;
    const float* row = h + (size_t)m * DMODEL;
    float ss = 0.f;
    for (int d = t; d < DMODEL; d += 64) { float v = row[d]; ss += v * v; }
    #pragma unroll
    for (int o = 32; o > 0; o >>= 1) ss += __shfl_xor(ss, o, 64);
    float sc = rsqrtf(ss / DMODEL + 1e-5f);
    u16* out = xn + (size_t)m * DMODEL;
    for (int d = t; d < DMODEL; d += 64) out[d] = f2bf(row[d] * sc * w[d]);
}

// 128x128-tile bf16 MFMA GEMM: out[m,n] = sum_k A[m,k]*W[n,k].
// If Cb != nullptr writes bf16 to Cb, else f32 (+resid) to Cf.
__global__ __launch_bounds__(256)
void k_mfma(const u16* __restrict__ A, int lda,
            const u16* __restrict__ W,
            const float* __restrict__ resid,
            float* __restrict__ Cf, u16* __restrict__ Cb,
            int N, int K) {
    __shared__ u16 As[128 * 32];
    __shared__ u16 Bs[128 * 32];
    const int t = threadIdx.x;
    const int w = t >> 6, l = t & 63;
    const int lane15 = l & 15, quad = l >> 4;
    const int wm = w >> 1, wn = w & 1;
    const int m0 = blockIdx.y * 128, n0 = blockIdx.x * 128;

    f32x4 acc[4][4];
    #pragma unroll
    for (int i = 0; i < 4; ++i)
        #pragma unroll
        for (int j = 0; j < 4; ++j)
            acc[i][j] = (f32x4){0.f, 0.f, 0.f, 0.f};

    for (int k0 = 0; k0 < K; k0 += 32) {
        __syncthreads();
        #pragma unroll
        for (int q = 0; q < 2; ++q) {
            int c = q * 256 + t;
            const u16* ga = A + (size_t)(m0 + (c >> 2)) * lda + k0 + (c & 3) * 8;
            __builtin_amdgcn_global_load_lds(
                (const __attribute__((address_space(1))) void*)ga,
                (__attribute__((address_space(3))) void*)&As[c * 8], 16, 0, 0);
            const u16* gb = W + (size_t)(n0 + (c >> 2)) * K + k0 + (c & 3) * 8;
            __builtin_amdgcn_global_load_lds(
                (const __attribute__((address_space(1))) void*)gb,
                (__attribute__((address_space(3))) void*)&Bs[c * 8], 16, 0, 0);
        }
        __syncthreads();

        bf16x8 af[4], bfrag[4];
        #pragma unroll
        for (int i = 0; i < 4; ++i)
            af[i] = *(const bf16x8*)&As[(wm * 64 + i * 16 + lane15) * 32 + quad * 8];
        #pragma unroll
        for (int j = 0; j < 4; ++j)
            bfrag[j] = *(const bf16x8*)&Bs[(wn * 64 + j * 16 + lane15) * 32 + quad * 8];
        #pragma unroll
        for (int i = 0; i < 4; ++i)
            #pragma unroll
            for (int j = 0; j < 4; ++j)
                acc[i][j] = __builtin_amdgcn_mfma_f32_16x16x32_bf16(
                    af[i], bfrag[j], acc[i][j], 0, 0, 0);
    }

    #pragma unroll
    for (int i = 0; i < 4; ++i) {
        #pragma unroll
        for (int r = 0; r < 4; ++r) {
            int row = m0 + wm * 64 + i * 16 + quad * 4 + r;
            #pragma unroll
            for (int j = 0; j < 4; ++j) {
                int col = n0 + wn * 64 + j * 16 + lane15;
                size_t idx = (size_t)row * N + col;
                if (Cb) {
                    Cb[idx] = f2bf(acc[i][j][r]);
                } else {
                    float v = acc[i][j][r];
                    if (resid) v += resid[idx];
                    Cf[idx] = v;
                }
            }
        }
    }
}

// 64x64-tile bf16 MFMA GEMM, f32 out + resid (out_proj)
__global__ __launch_bounds__(256)
void k_mfma64(const u16* __restrict__ A, int lda,
              const u16* __restrict__ W,
              const float* __restrict__ resid,
              float* __restrict__ C, int N, int K) {
    __shared__ u16 As[64 * 32];
    __shared__ u16 Bs[64 * 32];
    const int t = threadIdx.x;
    const int w = t >> 6, l = t & 63;
    const int lane15 = l & 15, quad = l >> 4;
    const int wm = w >> 1, wn = w & 1;
    const int m0 = blockIdx.y * 64, n0 = blockIdx.x * 64;

    f32x4 acc[2][2];
    #pragma unroll
    for (int i = 0; i < 2; ++i)
        #pragma unroll
        for (int j = 0; j < 2; ++j)
            acc[i][j] = (f32x4){0.f, 0.f, 0.f, 0.f};

    for (int k0 = 0; k0 < K; k0 += 32) {
        __syncthreads();
        {
            int c = t;
            const u16* ga = A + (size_t)(m0 + (c >> 2)) * lda + k0 + (c & 3) * 8;
            __builtin_amdgcn_global_load_lds(
                (const __attribute__((address_space(1))) void*)ga,
                (__attribute__((address_space(3))) void*)&As[c * 8], 16, 0, 0);
            const u16* gb = W + (size_t)(n0 + (c >> 2)) * K + k0 + (c & 3) * 8;
            __builtin_amdgcn_global_load_lds(
                (const __attribute__((address_space(1))) void*)gb,
                (__attribute__((address_space(3))) void*)&Bs[c * 8], 16, 0, 0);
        }
        __syncthreads();

        bf16x8 af[2], bfrag[2];
        #pragma unroll
        for (int i = 0; i < 2; ++i)
            af[i] = *(const bf16x8*)&As[(wm * 32 + i * 16 + lane15) * 32 + quad * 8];
        #pragma unroll
        for (int j = 0; j < 2; ++j)
            bfrag[j] = *(const bf16x8*)&Bs[(wn * 32 + j * 16 + lane15) * 32 + quad * 8];
        #pragma unroll
        for (int i = 0; i < 2; ++i)
            #pragma unroll
            for (int j = 0; j < 2; ++j)
                acc[i][j] = __builtin_amdgcn_mfma_f32_16x16x32_bf16(
                    af[i], bfrag[j], acc[i][j], 0, 0, 0);
    }

    #pragma unroll
    for (int i = 0; i < 2; ++i) {
        #pragma unroll
        for (int r = 0; r < 4; ++r) {
            int row = m0 + wm * 32 + i * 16 + quad * 4 + r;
            #pragma unroll
            for (int j = 0; j < 2; ++j) {
                int col = n0 + wn * 32 + j * 16 + lane15;
                size_t idx = (size_t)row * N + col;
                float v = acc[i][j][r];
                if (resid) v += resid[idx];
                C[idx] = v;
            }
        }
    }
}

// Fused conv + x_proj + dt + scan. One block per (batch, channel-quarter).
// Block: 320 threads (5 waves). LDS: u bf16 [32][1280] (80KB) + dbl f32 [32][80].
// Conv (all 1280 ch, duplicated across the 4 sibling blocks) -> u in LDS;
// x_proj via MFMA (M=32pad, N=80, K=1280) -> dbl in LDS;
// dt + selective scan per channel d = quarter*320 + tid -> y bf16 global.
__global__ __launch_bounds__(320, 2)
void k_ssm(const u16* __restrict__ urb,      // [MTOK][NPROJ] bf16 (u | res)
           const float* __restrict__ cw, const float* __restrict__ cb,
           const u16* __restrict__ wbx,      // [80][1280] bf16 (padded)
           const float* __restrict__ dtw,    // [1280][40]
           const float* __restrict__ dtb,    // [1280]
           const float* __restrict__ A_log,  // [1280][16]
           const float* __restrict__ Dsk,    // [1280]
           u16* __restrict__ y) {            // [MTOK][DINNER] bf16
    __shared__ u16  uL[32 * DINNER];         // 80 KB
    __shared__ float dblL[32][NDBLP];        // 10.24 KB
    const int b   = blockIdx.x >> 2;
    const int qt  = blockIdx.x & 3;
    const int tid = threadIdx.x;

    // ---------- phase 1: causal depthwise conv + silu -> uL (bf16)
    #pragma unroll
    for (int cc = 0; cc < 4; ++cc) {
        int c = cc * 320 + tid;
        float w0 = cw[c * 4 + 0], w1 = cw[c * 4 + 1];
        float w2 = cw[c * 4 + 2], w3 = cw[c * 4 + 3];
        float bias = cb[c];
        float x0 = 0.f, x1 = 0.f, x2 = 0.f;
        const u16* up = urb + (size_t)(b * SEQ) * NPROJ + c;
        for (int v = 0; v < SEQ; ++v) {
            float x3 = bf2f(up[(size_t)v * NPROJ]);
            float o = bias + w0 * x0 + w1 * x1 + w2 * x2 + w3 * x3;
            uL[v * DINNER + c] = f2bf(siluf(o));
            x0 = x1; x1 = x2; x2 = x3;
        }
        uL[30 * DINNER + c] = 0;
        uL[31 * DINNER + c] = 0;
    }
    __syncthreads();

    // ---------- phase 2: x_proj MFMA. 10 tile-jobs (2 mt x 5 nt) on 5 waves.
    {
        const int w = tid >> 6, l = tid & 63;
        const int lane15 = l & 15, quad = l >> 4;
        const int j0 = w * 2, j1 = w * 2 + 1;
        const int mt0 = j0 / 5, nt0 = j0 % 5;
        const int mt1 = j1 / 5, nt1 = j1 % 5;
        f32x4 acc0 = (f32x4){0.f, 0.f, 0.f, 0.f};
        f32x4 acc1 = (f32x4){0.f, 0.f, 0.f, 0.f};
        for (int k0 = 0; k0 < DINNER; k0 += 32) {
            bf16x8 a0 = *(const bf16x8*)&uL[(mt0 * 16 + lane15) * DINNER + k0 + quad * 8];
            bf16x8 b0 = *(const bf16x8*)&wbx[(size_t)(nt0 * 16 + lane15) * DINNER + k0 + quad * 8];
            acc0 = __builtin_amdgcn_mfma_f32_16x16x32_bf16(a0, b0, acc0, 0, 0, 0);
            bf16x8 a1 = *(const bf16x8*)&uL[(mt1 * 16 + lane15) * DINNER + k0 + quad * 8];
            bf16x8 b1 = *(const bf16x8*)&wbx[(size_t)(nt1 * 16 + lane15) * DINNER + k0 + quad * 8];
            acc1 = __builtin_amdgcn_mfma_f32_16x16x32_bf16(a1, b1, acc1, 0, 0, 0);
        }
        #pragma unroll
        for (int r = 0; r < 4; ++r) {
            dblL[mt0 * 16 + quad * 4 + r][nt0 * 16 + lane15] = acc0[r];
            dblL[mt1 * 16 + quad * 4 + r][nt1 * 16 + lane15] = acc1[r];
        }
    }
    __syncthreads();

    // ---------- phase 3: dt (softplus) + selective scan for channel d
    {
        const int d = qt * 320 + tid;
        float dtwr[DTRANK];
        #pragma unroll
        for (int r = 0; r < DTRANK; r += 4)
            *(float4*)&dtwr[r] = *(const float4*)&dtw[(size_t)d * DTRANK + r];
        float bias = dtb[d];
        float Ar[DSTATE];
        #pragma unroll
        for (int s = 0; s < DSTATE; ++s) Ar[s] = -__expf(A_log[(size_t)d * DSTATE + s]);
        float dsk = Dsk[d];
        float st[DSTATE];
        #pragma unroll
        for (int s = 0; s < DSTATE; ++s) st[s] = 0.f;

        const u16* rp = urb + (size_t)(b * SEQ) * NPROJ + DINNER + d;
        u16* yp = y + (size_t)(b * SEQ) * DINNER + d;

        for (int v = 0; v < SEQ; ++v) {
            float acc = bias;
            #pragma unroll
            for (int r = 0; r < DTRANK; r += 4) {
                float4 q = *(const float4*)&dblL[v][r];
                acc += q.x * dtwr[r] + q.y * dtwr[r + 1]
                     + q.z * dtwr[r + 2] + q.w * dtwr[r + 3];
            }
            float dlt = (acc > 20.f) ? acc : log1pf(__expf(acc));
            float Bv[DSTATE], Cv[DSTATE];
            #pragma unroll
            for (int r = 0; r < DSTATE; r += 4) {
                *(float4*)&Bv[r] = *(const float4*)&dblL[v][DTRANK + r];
                *(float4*)&Cv[r] = *(const float4*)&dblL[v][DTRANK + DSTATE + r];
            }
            float uu  = bf2f(uL[v * DINNER + d]);
            float res = bf2f(rp[(size_t)v * NPROJ]);
            float du = dlt * uu;
            float ya = 0.f;
            #pragma unroll
            for (int s = 0; s < DSTATE; ++s) {
                float dA = __expf(dlt * Ar[s]);
                st[s] = dA * st[s] + du * Bv[s];
                ya += st[s] * Cv[s];
            }
            yp[(size_t)v * DINNER] = f2bf((ya + uu * dsk) * siluf(res));
        }
    }
}

// final rmsnorm fused with reverse permutation
__global__ __launch_bounds__(64)
void k_final(const float* __restrict__ h, const int* __restrict__ vs,
             const float* __restrict__ w, float* __restrict__ out) {
    int mv = blockIdx.x;
    int v = mv % SEQ, b = mv / SEQ;
    int src = (v + vs[b]) % SEQ;
    const float* row = h + (size_t)(b * SEQ + src) * DMODEL;
    int t = threadIdx.x;
    float ss = 0.f;
    for (int d = t; d < DMODEL; d += 64) { float x = row[d]; ss += x * x; }
    #pragma unroll
    for (int o = 32; o > 0; o >>= 1) ss += __shfl_xor(ss, o, 64);
    float sc = rsqrtf(ss / DMODEL + 1e-5f);
    float* op = out + (size_t)mv * DMODEL;
    for (int d = t; d < DMODEL; d += 64) op[d] = row[d] * sc * w[d];
}

extern "C" void kernel_launch(void* const* d_in, const int* in_sizes, int n_in,
                              void* d_out, int out_size, void* d_ws, size_t ws_size,
                              hipStream_t stream) {
    const float* x      = (const float*)d_in[0];
    const int*   vs     = (const int*)d_in[1];
    const float* norm_w = (const float*)d_in[2];
    const float* in_w   = (const float*)d_in[3];
    const float* conv_w = (const float*)d_in[4];
    const float* conv_b = (const float*)d_in[5];
    const float* xp_w   = (const float*)d_in[6];
    const float* dt_w   = (const float*)d_in[7];
    const float* dt_b   = (const float*)d_in[8];
    const float* A_log  = (const float*)d_in[9];
    const float* Dsk    = (const float*)d_in[10];
    const float* out_w  = (const float*)d_in[11];
    const float* nfw    = (const float*)d_in[12];
    float* out = (float*)d_out;

    char* p = (char*)d_ws;
    float* h    = (float*)p; p += (size_t)MTOK * DMODEL * 4;
    u16*   xn   = (u16*)p;   p += (size_t)MTOK * DMODEL * 2;
    u16*   urb  = (u16*)p;   p += (size_t)MTOK * NPROJ * 2;
    u16*   y    = (u16*)p;   p += (size_t)MTOK * DINNER * 2;
    u16*   wbi4 = (u16*)p;   p += (size_t)NLAYER * NPROJ * DMODEL * 2;
    u16*   wbo4 = (u16*)p;   p += (size_t)NLAYER * DMODEL * DINNER * 2;
    u16*   wbx4 = (u16*)p;   p += (size_t)NLAYER * NDBLP * DINNER * 2;

    // hoisted weight conversions (once per call)
    k_f2bf<<<(NLAYER * NPROJ * DMODEL / 4 + 255) / 256, 256, 0, stream>>>(
        in_w, wbi4, NLAYER * NPROJ * DMODEL);
    k_f2bf<<<(NLAYER * DMODEL * DINNER / 4 + 255) / 256, 256, 0, stream>>>(
        out_w, wbo4, NLAYER * DMODEL * DINNER);
    k_f2bf_pad4<<<(NLAYER * NDBLP * DINNER / 4 + 255) / 256, 256, 0, stream>>>(
        xp_w, wbx4);

    k_permute<<<(MTOK * DMODEL + 255) / 256, 256, 0, stream>>>(x, vs, h);

    for (int l = 0; l < NLAYER; ++l) {
        k_rmsnorm<<<MTOK, 64, 0, stream>>>(h, norm_w + (size_t)l * DMODEL, xn);

        k_mfma<<<dim3(NPROJ / 128, MTOK / 128), 256, 0, stream>>>(
            xn, DMODEL, wbi4 + (size_t)l * NPROJ * DMODEL, nullptr,
            nullptr, urb, NPROJ, DMODEL);

        k_ssm<<<BATCH * 4, 320, 0, stream>>>(
            urb,
            conv_w + (size_t)l * DINNER * DCONV, conv_b + (size_t)l * DINNER,
            wbx4 + (size_t)l * NDBLP * DINNER,
            dt_w + (size_t)l * DINNER * DTRANK, dt_b + (size_t)l * DINNER,
            A_log + (size_t)l * DINNER * DSTATE, Dsk + (size_t)l * DINNER, y);

        k_mfma64<<<dim3(DMODEL / 64, MTOK / 64), 256, 0, stream>>>(
            y, DINNER, wbo4 + (size_t)l * DMODEL * DINNER, h, h, DMODEL, DINNER);
    }

    k_final<<<MTOK, 64, 0, stream>>>(h, vs, nfw, out);
}

// Round 5
// 575.440 us; speedup vs baseline: 1.0882x; 1.0882x over previous
//
#include <hip/hip_runtime.h>
#include <math.h>

#define NLAYER 4
#define DMODEL 640
#define DINNER 1280
#define DSTATE 16
#define DTRANK 40
#define DCONV  4
#define BATCH  64
#define SEQ    30
#define MTOK   (BATCH*SEQ)       // 1920
#define NPROJ  (2*DINNER)        // 2560
#define NDBL   (DTRANK+2*DSTATE) // 72
#define NDBLP  80                // padded N for x_proj MFMA
#define KSEGS  4
#define KSEG   (DINNER/KSEGS)    // 320

typedef unsigned short u16;
typedef __bf16 bf16x8 __attribute__((ext_vector_type(8)));
typedef float  f32x4  __attribute__((ext_vector_type(4)));

__device__ __forceinline__ float siluf(float x) {
    return x / (1.0f + __expf(-x));
}

__device__ __forceinline__ u16 f2bf(float f) {
    unsigned int u = __float_as_uint(f);
    u += 0x7fffu + ((u >> 16) & 1u);
    return (u16)(u >> 16);
}

__device__ __forceinline__ float bf2f(u16 b) {
    return __uint_as_float(((unsigned int)b) << 16);
}

// h[b,v,:] = x[b,(v + SEQ - vs[b]) % SEQ, :]
__global__ void k_permute(const float* __restrict__ x, const int* __restrict__ vs,
                          float* __restrict__ h) {
    int idx = blockIdx.x * blockDim.x + threadIdx.x;
    if (idx >= MTOK * DMODEL) return;
    int d  = idx % DMODEL;
    int mv = idx / DMODEL;
    int v  = mv % SEQ;
    int b  = mv / SEQ;
    int src = (v + SEQ - vs[b]) % SEQ;
    h[idx] = x[(b * SEQ + src) * DMODEL + d];
}

// fp32 -> bf16, 4/thread
__global__ void k_f2bf(const float* __restrict__ src, u16* __restrict__ dst, int n) {
    int i = (blockIdx.x * blockDim.x + threadIdx.x) * 4;
    if (i >= n) return;
    float4 v = *(const float4*)(src + i);
    ushort4 o;
    o.x = f2bf(v.x); o.y = f2bf(v.y); o.z = f2bf(v.z); o.w = f2bf(v.w);
    *(ushort4*)(dst + i) = o;
}

// xp_w [4][72][1280] fp32 -> [4][80][1280] bf16, rows 72..79 of each layer zeroed
__global__ void k_f2bf_pad4(const float* __restrict__ src, u16* __restrict__ dst) {
    int i = (blockIdx.x * blockDim.x + threadIdx.x) * 4;
    if (i >= NLAYER * NDBLP * DINNER) return;
    int layer = i / (NDBLP * DINNER);
    int rem   = i % (NDBLP * DINNER);
    int row   = rem / DINNER;
    int col   = rem % DINNER;
    ushort4 o = make_ushort4(0, 0, 0, 0);
    if (row < NDBL) {
        float4 v = *(const float4*)(src + (size_t)layer * NDBL * DINNER
                                        + (size_t)row * DINNER + col);
        o.x = f2bf(v.x); o.y = f2bf(v.y); o.z = f2bf(v.z); o.w = f2bf(v.w);
    }
    *(ushort4*)(dst + i) = o;
}

// one wave per token: xn_bf16 = h * rsqrt(mean(h^2)+eps) * w
__global__ __launch_bounds__(64)
void k_rmsnorm(const float* __restrict__ h, const float* __restrict__ w,
               u16* __restrict__ xn) {
    int m = blockIdx.x;
    int t = threadIdx.x;
    const float* row = h + (size_t)m * DMODEL;
    float ss = 0.f;
    for (int d = t; d < DMODEL; d += 64) { float v = row[d]; ss += v * v; }
    #pragma unroll
    for (int o = 32; o > 0; o >>= 1) ss += __shfl_xor(ss, o, 64);
    float sc = rsqrtf(ss / DMODEL + 1e-5f);
    u16* out = xn + (size_t)m * DMODEL;
    for (int d = t; d < DMODEL; d += 64) out[d] = f2bf(row[d] * sc * w[d]);
}

// 128x128-tile bf16 MFMA GEMM: out[m,n] = sum_k A[m,k]*W[n,k].
// If Cb != nullptr writes bf16 to Cb, else f32 (+resid) to Cf.
__global__ __launch_bounds__(256)
void k_mfma(const u16* __restrict__ A, int lda,
            const u16* __restrict__ W,
            const float* __restrict__ resid,
            float* __restrict__ Cf, u16* __restrict__ Cb,
            int N, int K) {
    __shared__ u16 As[128 * 32];
    __shared__ u16 Bs[128 * 32];
    const int t = threadIdx.x;
    const int w = t >> 6, l = t & 63;
    const int lane15 = l & 15, quad = l >> 4;
    const int wm = w >> 1, wn = w & 1;
    const int m0 = blockIdx.y * 128, n0 = blockIdx.x * 128;

    f32x4 acc[4][4];
    #pragma unroll
    for (int i = 0; i < 4; ++i)
        #pragma unroll
        for (int j = 0; j < 4; ++j)
            acc[i][j] = (f32x4){0.f, 0.f, 0.f, 0.f};

    for (int k0 = 0; k0 < K; k0 += 32) {
        __syncthreads();
        #pragma unroll
        for (int q = 0; q < 2; ++q) {
            int c = q * 256 + t;
            const u16* ga = A + (size_t)(m0 + (c >> 2)) * lda + k0 + (c & 3) * 8;
            __builtin_amdgcn_global_load_lds(
                (const __attribute__((address_space(1))) void*)ga,
                (__attribute__((address_space(3))) void*)&As[c * 8], 16, 0, 0);
            const u16* gb = W + (size_t)(n0 + (c >> 2)) * K + k0 + (c & 3) * 8;
            __builtin_amdgcn_global_load_lds(
                (const __attribute__((address_space(1))) void*)gb,
                (__attribute__((address_space(3))) void*)&Bs[c * 8], 16, 0, 0);
        }
        __syncthreads();

        bf16x8 af[4], bfrag[4];
        #pragma unroll
        for (int i = 0; i < 4; ++i)
            af[i] = *(const bf16x8*)&As[(wm * 64 + i * 16 + lane15) * 32 + quad * 8];
        #pragma unroll
        for (int j = 0; j < 4; ++j)
            bfrag[j] = *(const bf16x8*)&Bs[(wn * 64 + j * 16 + lane15) * 32 + quad * 8];
        #pragma unroll
        for (int i = 0; i < 4; ++i)
            #pragma unroll
            for (int j = 0; j < 4; ++j)
                acc[i][j] = __builtin_amdgcn_mfma_f32_16x16x32_bf16(
                    af[i], bfrag[j], acc[i][j], 0, 0, 0);
    }

    #pragma unroll
    for (int i = 0; i < 4; ++i) {
        #pragma unroll
        for (int r = 0; r < 4; ++r) {
            int row = m0 + wm * 64 + i * 16 + quad * 4 + r;
            #pragma unroll
            for (int j = 0; j < 4; ++j) {
                int col = n0 + wn * 64 + j * 16 + lane15;
                size_t idx = (size_t)row * N + col;
                if (Cb) {
                    Cb[idx] = f2bf(acc[i][j][r]);
                } else {
                    float v = acc[i][j][r];
                    if (resid) v += resid[idx];
                    Cf[idx] = v;
                }
            }
        }
    }
}

// 64x64-tile bf16 MFMA GEMM, f32 out + resid (out_proj)
__global__ __launch_bounds__(256)
void k_mfma64(const u16* __restrict__ A, int lda,
              const u16* __restrict__ W,
              const float* __restrict__ resid,
              float* __restrict__ C, int N, int K) {
    __shared__ u16 As[64 * 32];
    __shared__ u16 Bs[64 * 32];
    const int t = threadIdx.x;
    const int w = t >> 6, l = t & 63;
    const int lane15 = l & 15, quad = l >> 4;
    const int wm = w >> 1, wn = w & 1;
    const int m0 = blockIdx.y * 64, n0 = blockIdx.x * 64;

    f32x4 acc[2][2];
    #pragma unroll
    for (int i = 0; i < 2; ++i)
        #pragma unroll
        for (int j = 0; j < 2; ++j)
            acc[i][j] = (f32x4){0.f, 0.f, 0.f, 0.f};

    for (int k0 = 0; k0 < K; k0 += 32) {
        __syncthreads();
        {
            int c = t;
            const u16* ga = A + (size_t)(m0 + (c >> 2)) * lda + k0 + (c & 3) * 8;
            __builtin_amdgcn_global_load_lds(
                (const __attribute__((address_space(1))) void*)ga,
                (__attribute__((address_space(3))) void*)&As[c * 8], 16, 0, 0);
            const u16* gb = W + (size_t)(n0 + (c >> 2)) * K + k0 + (c & 3) * 8;
            __builtin_amdgcn_global_load_lds(
                (const __attribute__((address_space(1))) void*)gb,
                (__attribute__((address_space(3))) void*)&Bs[c * 8], 16, 0, 0);
        }
        __syncthreads();

        bf16x8 af[2], bfrag[2];
        #pragma unroll
        for (int i = 0; i < 2; ++i)
            af[i] = *(const bf16x8*)&As[(wm * 32 + i * 16 + lane15) * 32 + quad * 8];
        #pragma unroll
        for (int j = 0; j < 2; ++j)
            bfrag[j] = *(const bf16x8*)&Bs[(wn * 32 + j * 16 + lane15) * 32 + quad * 8];
        #pragma unroll
        for (int i = 0; i < 2; ++i)
            #pragma unroll
            for (int j = 0; j < 2; ++j)
                acc[i][j] = __builtin_amdgcn_mfma_f32_16x16x32_bf16(
                    af[i], bfrag[j], acc[i][j], 0, 0, 0);
    }

    #pragma unroll
    for (int i = 0; i < 2; ++i) {
        #pragma unroll
        for (int r = 0; r < 4; ++r) {
            int row = m0 + wm * 32 + i * 16 + quad * 4 + r;
            #pragma unroll
            for (int j = 0; j < 2; ++j) {
                int col = n0 + wn * 32 + j * 16 + lane15;
                size_t idx = (size_t)row * N + col;
                float v = acc[i][j][r];
                if (resid) v += resid[idx];
                C[idx] = v;
            }
        }
    }
}

// causal depthwise conv + silu: one thread per (b,c). bf16 in (u half of urb),
// bf16 out (compact ubf [MTOK][DINNER]). 30 loads fully unrolled (independent
// addresses -> compiler pipelines them), then compute + 30 stores.
__global__ __launch_bounds__(256)
void k_conv(const u16* __restrict__ urb, const float* __restrict__ cw,
            const float* __restrict__ cb, u16* __restrict__ ubf) {
    int idx = blockIdx.x * 256 + threadIdx.x;   // b*DINNER + c
    int c = idx % DINNER;
    int b = idx / DINNER;
    const u16* up = urb + (size_t)(b * SEQ) * NPROJ + c;
    float xv[SEQ];
    #pragma unroll
    for (int v = 0; v < SEQ; ++v) xv[v] = bf2f(up[(size_t)v * NPROJ]);
    float w0 = cw[c * 4 + 0], w1 = cw[c * 4 + 1];
    float w2 = cw[c * 4 + 2], w3 = cw[c * 4 + 3];
    float bias = cb[c];
    u16* op = ubf + (size_t)(b * SEQ) * DINNER + c;
    float x0 = 0.f, x1 = 0.f, x2 = 0.f;
    #pragma unroll
    for (int v = 0; v < SEQ; ++v) {
        float x3 = xv[v];
        float o = bias + w0 * x0 + w1 * x1 + w2 * x2 + w3 * x3;
        op[(size_t)v * DINNER] = f2bf(siluf(o));
        x0 = x1; x1 = x2; x2 = x3;
    }
}

// x_proj: split-K bf16 MFMA. A=ubf [MTOK,DINNER], B=wbx [80,DINNER].
// Grid (KSEGS, MTOK/64), 256 thr. Writes fp32 partials dblp[seg][MTOK][80].
__global__ __launch_bounds__(256)
void k_xproj(const u16* __restrict__ ubf, const u16* __restrict__ wbx,
             float* __restrict__ dblp) {
    __shared__ u16 As[64 * 32];
    __shared__ u16 Bs[NDBLP * 32];
    const int t = threadIdx.x;
    const int w = t >> 6, l = t & 63;
    const int lane15 = l & 15, quad = l >> 4;
    const int seg = blockIdx.x;
    const int m0 = blockIdx.y * 64;
    const int kb = seg * KSEG;

    f32x4 acc[5];
    #pragma unroll
    for (int j = 0; j < 5; ++j) acc[j] = (f32x4){0.f, 0.f, 0.f, 0.f};

    for (int k0 = 0; k0 < KSEG; k0 += 32) {
        __syncthreads();
        {
            int c = t;
            const u16* ga = ubf + (size_t)(m0 + (c >> 2)) * DINNER + kb + k0 + (c & 3) * 8;
            __builtin_amdgcn_global_load_lds(
                (const __attribute__((address_space(1))) void*)ga,
                (__attribute__((address_space(3))) void*)&As[c * 8], 16, 0, 0);
            const u16* gb = wbx + (size_t)(c >> 2) * DINNER + kb + k0 + (c & 3) * 8;
            __builtin_amdgcn_global_load_lds(
                (const __attribute__((address_space(1))) void*)gb,
                (__attribute__((address_space(3))) void*)&Bs[c * 8], 16, 0, 0);
        }
        if (t < 64) {
            int c = 256 + t;
            const u16* gb = wbx + (size_t)(c >> 2) * DINNER + kb + k0 + (c & 3) * 8;
            __builtin_amdgcn_global_load_lds(
                (const __attribute__((address_space(1))) void*)gb,
                (__attribute__((address_space(3))) void*)&Bs[c * 8], 16, 0, 0);
        }
        __syncthreads();

        bf16x8 af = *(const bf16x8*)&As[(w * 16 + lane15) * 32 + quad * 8];
        #pragma unroll
        for (int j = 0; j < 5; ++j) {
            bf16x8 bfrag = *(const bf16x8*)&Bs[(j * 16 + lane15) * 32 + quad * 8];
            acc[j] = __builtin_amdgcn_mfma_f32_16x16x32_bf16(af, bfrag, acc[j], 0, 0, 0);
        }
    }

    float* outp = dblp + (size_t)seg * MTOK * NDBLP;
    #pragma unroll
    for (int r = 0; r < 4; ++r) {
        int row = m0 + w * 16 + quad * 4 + r;
        #pragma unroll
        for (int j = 0; j < 5; ++j) {
            int col = j * 16 + lane15;
            outp[(size_t)row * NDBLP + col] = acc[j][r];
        }
    }
}

// Fused dt + selective scan. One thread per (b,d). Grid 64*10 blocks x 128 thr.
// Stage summed dbl rows [30][72] in LDS (8.6KB); dt-dot via LDS broadcasts;
// 16-state scan in registers; y bf16 coalesced.
__global__ __launch_bounds__(128)
void k_dtscan(const u16* __restrict__ ubf, const u16* __restrict__ urb,
              const float* __restrict__ dblp,
              const float* __restrict__ dtw, const float* __restrict__ dtb,
              const float* __restrict__ A_log, const float* __restrict__ Dsk,
              u16* __restrict__ y) {
    __shared__ float dtL[SEQ][NDBL];   // [30][72]
    const int b  = blockIdx.x / (DINNER / 128);
    const int dc = blockIdx.x % (DINNER / 128);
    const int d  = dc * 128 + threadIdx.x;

    for (int t = threadIdx.x; t < SEQ * NDBL; t += 128) {
        int v = t / NDBL, col = t % NDBL;
        float s = 0.f;
        #pragma unroll
        for (int sg = 0; sg < KSEGS; ++sg)
            s += dblp[(size_t)sg * MTOK * NDBLP + (size_t)(b * SEQ + v) * NDBLP + col];
        dtL[v][col] = s;
    }
    __syncthreads();

    float dtwr[DTRANK];
    #pragma unroll
    for (int r = 0; r < DTRANK; r += 4)
        *(float4*)&dtwr[r] = *(const float4*)&dtw[(size_t)d * DTRANK + r];
    float bias = dtb[d];
    float Ar[DSTATE];
    #pragma unroll
    for (int s = 0; s < DSTATE; ++s) Ar[s] = -__expf(A_log[(size_t)d * DSTATE + s]);
    float dsk = Dsk[d];
    float st[DSTATE];
    #pragma unroll
    for (int s = 0; s < DSTATE; ++s) st[s] = 0.f;

    const u16* up = ubf + (size_t)(b * SEQ) * DINNER + d;
    const u16* rp = urb + (size_t)(b * SEQ) * NPROJ + DINNER + d;
    u16* yp = y + (size_t)(b * SEQ) * DINNER + d;

    for (int v = 0; v < SEQ; ++v) {
        float acc = bias;
        #pragma unroll
        for (int r = 0; r < DTRANK; ++r) acc += dtL[v][r] * dtwr[r];
        float dlt = (acc > 20.f) ? acc : log1pf(__expf(acc));
        float uu  = bf2f(up[(size_t)v * DINNER]);
        float res = bf2f(rp[(size_t)v * NPROJ]);
        float du  = dlt * uu;
        float ya  = 0.f;
        #pragma unroll
        for (int s = 0; s < DSTATE; ++s) {
            float dA = __expf(dlt * Ar[s]);
            st[s] = dA * st[s] + du * dtL[v][DTRANK + s];
            ya += st[s] * dtL[v][DTRANK + DSTATE + s];
        }
        yp[(size_t)v * DINNER] = f2bf((ya + uu * dsk) * siluf(res));
    }
}

// final rmsnorm fused with reverse permutation
__global__ __launch_bounds__(64)
void k_final(const float* __restrict__ h, const int* __restrict__ vs,
             const float* __restrict__ w, float* __restrict__ out) {
    int mv = blockIdx.x;
    int v = mv % SEQ, b = mv / SEQ;
    int src = (v + vs[b]) % SEQ;
    const float* row = h + (size_t)(b * SEQ + src) * DMODEL;
    int t = threadIdx.x;
    float ss = 0.f;
    for (int d = t; d < DMODEL; d += 64) { float x = row[d]; ss += x * x; }
    #pragma unroll
    for (int o = 32; o > 0; o >>= 1) ss += __shfl_xor(ss, o, 64);
    float sc = rsqrtf(ss / DMODEL + 1e-5f);
    float* op = out + (size_t)mv * DMODEL;
    for (int d = t; d < DMODEL; d += 64) op[d] = row[d] * sc * w[d];
}

extern "C" void kernel_launch(void* const* d_in, const int* in_sizes, int n_in,
                              void* d_out, int out_size, void* d_ws, size_t ws_size,
                              hipStream_t stream) {
    const float* x      = (const float*)d_in[0];
    const int*   vs     = (const int*)d_in[1];
    const float* norm_w = (const float*)d_in[2];
    const float* in_w   = (const float*)d_in[3];
    const float* conv_w = (const float*)d_in[4];
    const float* conv_b = (const float*)d_in[5];
    const float* xp_w   = (const float*)d_in[6];
    const float* dt_w   = (const float*)d_in[7];
    const float* dt_b   = (const float*)d_in[8];
    const float* A_log  = (const float*)d_in[9];
    const float* Dsk    = (const float*)d_in[10];
    const float* out_w  = (const float*)d_in[11];
    const float* nfw    = (const float*)d_in[12];
    float* out = (float*)d_out;

    char* p = (char*)d_ws;
    float* h    = (float*)p; p += (size_t)MTOK * DMODEL * 4;
    u16*   xn   = (u16*)p;   p += (size_t)MTOK * DMODEL * 2;
    u16*   urb  = (u16*)p;   p += (size_t)MTOK * NPROJ * 2;
    u16*   ubf  = (u16*)p;   p += (size_t)MTOK * DINNER * 2;
    float* dblp = (float*)p; p += (size_t)KSEGS * MTOK * NDBLP * 4;
    u16*   y    = (u16*)p;   p += (size_t)MTOK * DINNER * 2;
    u16*   wbi4 = (u16*)p;   p += (size_t)NLAYER * NPROJ * DMODEL * 2;
    u16*   wbo4 = (u16*)p;   p += (size_t)NLAYER * DMODEL * DINNER * 2;
    u16*   wbx4 = (u16*)p;   p += (size_t)NLAYER * NDBLP * DINNER * 2;

    // hoisted weight conversions (once per call)
    k_f2bf<<<(NLAYER * NPROJ * DMODEL / 4 + 255) / 256, 256, 0, stream>>>(
        in_w, wbi4, NLAYER * NPROJ * DMODEL);
    k_f2bf<<<(NLAYER * DMODEL * DINNER / 4 + 255) / 256, 256, 0, stream>>>(
        out_w, wbo4, NLAYER * DMODEL * DINNER);
    k_f2bf_pad4<<<(NLAYER * NDBLP * DINNER / 4 + 255) / 256, 256, 0, stream>>>(
        xp_w, wbx4);

    k_permute<<<(MTOK * DMODEL + 255) / 256, 256, 0, stream>>>(x, vs, h);

    for (int l = 0; l < NLAYER; ++l) {
        k_rmsnorm<<<MTOK, 64, 0, stream>>>(h, norm_w + (size_t)l * DMODEL, xn);

        k_mfma<<<dim3(NPROJ / 128, MTOK / 128), 256, 0, stream>>>(
            xn, DMODEL, wbi4 + (size_t)l * NPROJ * DMODEL, nullptr,
            nullptr, urb, NPROJ, DMODEL);

        k_conv<<<BATCH * DINNER / 256, 256, 0, stream>>>(
            urb, conv_w + (size_t)l * DINNER * DCONV, conv_b + (size_t)l * DINNER, ubf);

        k_xproj<<<dim3(KSEGS, MTOK / 64), 256, 0, stream>>>(
            ubf, wbx4 + (size_t)l * NDBLP * DINNER, dblp);

        k_dtscan<<<BATCH * (DINNER / 128), 128, 0, stream>>>(
            ubf, urb, dblp,
            dt_w + (size_t)l * DINNER * DTRANK, dt_b + (size_t)l * DINNER,
            A_log + (size_t)l * DINNER * DSTATE, Dsk + (size_t)l * DINNER, y);

        k_mfma64<<<dim3(DMODEL / 64, MTOK / 64), 256, 0, stream>>>(
            y, DINNER, wbo4 + (size_t)l * DMODEL * DINNER, h, h, DMODEL, DINNER);
    }

    k_final<<<MTOK, 64, 0, stream>>>(h, vs, nfw, out);
}